// Round 8
// baseline (435.355 us; speedup 1.0000x reference)
//
#include <hip/hip_runtime.h>
#include <hip/hip_bf16.h>
#include <stdint.h>
#include <stddef.h>
#include <math.h>

typedef _Float16 f16;
typedef __attribute__((ext_vector_type(8))) _Float16 f16x8;  // 4 VGPRs (MFMA A/B)
typedef __attribute__((ext_vector_type(4))) float    f32x4;  // MFMA C/D

constexpr int BM = 128, BN = 128, BK = 64;   // half-splitk tiles

// async global->LDS DMA, 16 B/lane; LDS dest = wave-uniform base + lane*16
#define GLOAD_LDS16(gp, lp)                                        \
    __builtin_amdgcn_global_load_lds(                              \
        (const __attribute__((address_space(1))) unsigned int*)(gp),\
        (__attribute__((address_space(3))) unsigned int*)(lp), 16, 0, 0)

// one MFMA cluster: 16 x mfma_f32_16x16x32_f16 wrapped in setprio (T5)
#define MFMA_TILE(AV, BV)                                                     \
    do {                                                                      \
        __builtin_amdgcn_s_setprio(1);                                        \
        _Pragma("unroll")                                                     \
        for (int mi_ = 0; mi_ < 4; ++mi_)                                     \
            _Pragma("unroll")                                                 \
            for (int ni_ = 0; ni_ < 4; ++ni_)                                 \
                acc[mi_][ni_] = __builtin_amdgcn_mfma_f32_16x16x32_f16(       \
                    (AV)[mi_], (BV)[ni_], acc[mi_][ni_], 0, 0, 0);            \
        __builtin_amdgcn_s_setprio(0);                                        \
    } while (0)

#define SGB __builtin_amdgcn_sched_group_barrier
// sched masks (m137): MFMA=0x8, VMEM_READ=0x20, DS_READ=0x100

// ===========================================================================
// Pipelined 2-term GEMM: C = (Ah+Al) @ B^T, f16 in / fp32 accum.
// BM=128, BN=256, BK=64, 512 threads = 8 waves (2M x 4N), 64x64 out/wave.
//
// Round-8 restructure (B DIRECT-TO-REGISTER): round 7 proved the kernel is
// not memory-bound (FETCH -64% via XCD swizzle, dur unchanged) and that the
// stall is the LDS pipe (24 ds_read/wave + 64KB DMA-writes ~= 2800 cyc/CU/
// tile) serializing with MFMA (2480) under barrier phase-alignment. Fix:
// B fragments load straight from global to VGPR (B is 2-way shared -> 2x L2
// reads, cheap on the idle VMEM path; lane layout = plain strided 16B load).
// Removes 32KB/tile DMA + 8/24 ds_reads -> LDS ~1790 cyc < MFMA 2480 ->
// MFMA-bound. A (4-way shared) stays LDS-staged; LDS = 64 KiB double-buffer
// [Ah 16K | Al 16K]. B loads issue first (latency hidden under MFMA).
template <int EPI>
__global__ __launch_bounds__(512, 2) void gemm8_a2(
    const f16* __restrict__ Ah, const f16* __restrict__ Al,
    const f16* __restrict__ B,
    float* __restrict__ Cf, f16* __restrict__ Co, f16* __restrict__ Clo,
    int M, int N, int K)
{
    // bijective XCD remap: id%8 = XCD; XCD k -> contiguous j-range (L2 reuse)
    const int gx  = gridDim.x;
    const int nwg = gx * gridDim.y;
    const int id  = blockIdx.y * gx + blockIdx.x;
    const int cpx = nwg >> 3;
    const int j   = (id & 7) * cpx + (id >> 3);
    const int bx  = j % gx;
    const int by  = j / gx;

    const int tid   = threadIdx.x;
    const int lane  = tid & 63;
    const int wave  = tid >> 6;   // 0..7
    const int wm    = wave >> 2;  // 0..1  (M)
    const int wn    = wave & 3;   // 0..3  (N)
    const int lrow  = lane & 15;
    const int lquad = lane >> 4;

    __shared__ f16 lds[2][16384];   // 64 KiB total: [Ah 16KB | Al 16KB] x2

    const int row0 = by * 128;
    const int col0 = bx * 256;

    const int srow = tid >> 3;                       // 0..63 (row within unit)
    const int scol = ((tid & 7) ^ (srow & 7)) * 8;   // pre-swizzled source col
    const int loff = wave * 512;                     // wave slice inside a unit

    const int g0 = ((lquad)     ^ (lrow & 7)) * 8;   // swizzled group, kk=0
    const int g1 = ((4 + lquad) ^ (lrow & 7)) * 8;   // swizzled group, kk=1

    const int arow = (wm * 64 + lrow) * 64;           // A frag base (elems)

    const f16* gAh = Ah + (size_t)(row0 + srow) * K + scol;
    const f16* gAl = Al + (size_t)(row0 + srow) * K + scol;
    // B direct-to-reg base: row = col0 + wn*64 + lrow, col = lquad*8
    const f16* gBr = B + (size_t)(col0 + wn * 64 + lrow) * K + lquad * 8;
    const size_t r64 = (size_t)64 * K;
    const size_t r16 = (size_t)16 * K;

    f32x4 acc[4][4];
    const f32x4 fz = {0.f, 0.f, 0.f, 0.f};
    #pragma unroll
    for (int i = 0; i < 4; ++i)
        #pragma unroll
        for (int jj = 0; jj < 4; ++jj) acc[i][jj] = fz;

    const int nt = K / 64;

    // prologue: stage A tile 0 into buffer 0
    GLOAD_LDS16(gAh,       &lds[0][loff]);
    GLOAD_LDS16(gAh + r64, &lds[0][4096 + loff]);
    GLOAD_LDS16(gAl,       &lds[0][8192 + loff]);
    GLOAD_LDS16(gAl + r64, &lds[0][12288 + loff]);
    asm volatile("s_waitcnt vmcnt(0)");
    __builtin_amdgcn_s_barrier();

    for (int t = 0; t < nt; ++t) {
        const f16* bufc = &lds[t & 1][0];
        f16* bufn = &lds[(t + 1) & 1][0];
        // branchless prefetch target (last tile refetches itself: harmless)
        const size_t kn = (size_t)((t + 1 < nt) ? t + 1 : t) * 64;
        const size_t kb = (size_t)t * 64;

        f16x8 ah0[4], ah1[4], al0[4], al1[4], bv0[4], bv1[4];

        // ---- B direct loads (8 VMEM_READ, longest latency -> first)
        #pragma unroll
        for (int ni = 0; ni < 4; ++ni)
            bv0[ni] = *(const f16x8*)(gBr + (size_t)ni * r16 + kb);
        #pragma unroll
        for (int ni = 0; ni < 4; ++ni)
            bv1[ni] = *(const f16x8*)(gBr + (size_t)ni * r16 + kb + 32);

        // ---- A cluster-0 reads (4 DS)
        #pragma unroll
        for (int mi = 0; mi < 4; ++mi)
            ah0[mi] = *(const f16x8*)&bufc[arow + mi * 1024 + g0];

        // ---- stage A(t+1) (4 VMEM_READ)
        GLOAD_LDS16(gAh + kn,       &bufn[loff]);
        GLOAD_LDS16(gAh + r64 + kn, &bufn[4096 + loff]);
        GLOAD_LDS16(gAl + kn,       &bufn[ 8192 + loff]);
        GLOAD_LDS16(gAl + r64 + kn, &bufn[12288 + loff]);

        // ---- remaining A reads (12 DS)
        #pragma unroll
        for (int mi = 0; mi < 4; ++mi)
            ah1[mi] = *(const f16x8*)&bufc[arow + mi * 1024 + g1];
        #pragma unroll
        for (int mi = 0; mi < 4; ++mi)
            al0[mi] = *(const f16x8*)&bufc[8192 + arow + mi * 1024 + g0];
        #pragma unroll
        for (int mi = 0; mi < 4; ++mi)
            al1[mi] = *(const f16x8*)&bufc[8192 + arow + mi * 1024 + g1];

        MFMA_TILE(ah0, bv0);
        MFMA_TILE(ah1, bv1);
        MFMA_TILE(al0, bv0);
        MFMA_TILE(al1, bv1);

        // schedule pin: B8 | DS4 | DMA4 | DS12 | MFMA64
        SGB(0x20,  8, 0);
        SGB(0x100, 4, 0);
        SGB(0x20,  4, 0);
        SGB(0x100, 12, 0);
        SGB(0x8,  64, 0);

        asm volatile("s_waitcnt vmcnt(0)");   // A(t+1) DMA landed (own wave)
        __builtin_amdgcn_s_barrier();
    }

    // epilogue: D element (row = lquad*4 + r, col = lrow) within 16x16 tiles
    #pragma unroll
    for (int mi = 0; mi < 4; ++mi) {
        #pragma unroll
        for (int ni = 0; ni < 4; ++ni) {
            #pragma unroll
            for (int r = 0; r < 4; ++r) {
                const int row = row0 + wm * 64 + mi * 16 + lquad * 4 + r;
                const int col = col0 + wn * 64 + ni * 16 + lrow;
                const size_t idx = (size_t)row * N + col;
                const float v = acc[mi][ni][r];
                if (EPI == 0) {
                    Cf[idx] = v;
                } else {
                    const f16 h = (f16)v;
                    Co[idx]  = h;
                    Clo[idx] = (f16)(v - (float)h);
                }
            }
        }
    }
}

// ===========================================================================
// S-GEMM main dispatch: the 256 FULLY-LIVE causal jobs, one block each,
// perfectly balanced 1 block/CU. Job map: r = floor(sqrt(j)); u = j - r^2;
// (by,bx) = u<r ? (2r, u) : (2r+1, u-r). XCD remap b -> j = (b&7)*32 + (b>>3).
// Same B-direct-to-reg single-BB body as gemm8_a2.
__global__ __launch_bounds__(512, 2) void gemm8_s_jobs(
    const f16* __restrict__ Ah, const f16* __restrict__ Al,
    const f16* __restrict__ B,
    float* __restrict__ Cf, int N, int K)
{
    const int b = blockIdx.x;
    const int j = (b & 7) * 32 + (b >> 3);
    int r = (int)sqrtf((float)j);
    while (r * r > j) --r;
    while ((r + 1) * (r + 1) <= j) ++r;
    const int u = j - r * r;
    const int by = (u < r) ? 2 * r : 2 * r + 1;
    const int bx = (u < r) ? u : u - r;

    const int tid   = threadIdx.x;
    const int lane  = tid & 63;
    const int wave  = tid >> 6;
    const int wm    = wave >> 2;
    const int wn    = wave & 3;
    const int lrow  = lane & 15;
    const int lquad = lane >> 4;

    __shared__ f16 lds[2][16384];   // 64 KiB

    const int row0 = by * 128;
    const int col0 = bx * 256;

    const int srow = tid >> 3;
    const int scol = ((tid & 7) ^ (srow & 7)) * 8;
    const int loff = wave * 512;

    const int g0 = ((lquad)     ^ (lrow & 7)) * 8;
    const int g1 = ((4 + lquad) ^ (lrow & 7)) * 8;

    const int arow = (wm * 64 + lrow) * 64;

    const f16* gAh = Ah + (size_t)(row0 + srow) * K + scol;
    const f16* gAl = Al + (size_t)(row0 + srow) * K + scol;
    const f16* gBr = B + (size_t)(col0 + wn * 64 + lrow) * K + lquad * 8;
    const size_t r64 = (size_t)64 * K;
    const size_t r16 = (size_t)16 * K;

    f32x4 acc[4][4];
    const f32x4 fz = {0.f, 0.f, 0.f, 0.f};
    #pragma unroll
    for (int i = 0; i < 4; ++i)
        #pragma unroll
        for (int jj = 0; jj < 4; ++jj) acc[i][jj] = fz;

    const int nt = K / 64;

    GLOAD_LDS16(gAh,       &lds[0][loff]);
    GLOAD_LDS16(gAh + r64, &lds[0][4096 + loff]);
    GLOAD_LDS16(gAl,       &lds[0][8192 + loff]);
    GLOAD_LDS16(gAl + r64, &lds[0][12288 + loff]);
    asm volatile("s_waitcnt vmcnt(0)");
    __builtin_amdgcn_s_barrier();

    for (int t = 0; t < nt; ++t) {
        const f16* bufc = &lds[t & 1][0];
        f16* bufn = &lds[(t + 1) & 1][0];
        const size_t kn = (size_t)((t + 1 < nt) ? t + 1 : t) * 64;
        const size_t kb = (size_t)t * 64;

        f16x8 ah0[4], ah1[4], al0[4], al1[4], bv0[4], bv1[4];

        #pragma unroll
        for (int ni = 0; ni < 4; ++ni)
            bv0[ni] = *(const f16x8*)(gBr + (size_t)ni * r16 + kb);
        #pragma unroll
        for (int ni = 0; ni < 4; ++ni)
            bv1[ni] = *(const f16x8*)(gBr + (size_t)ni * r16 + kb + 32);

        #pragma unroll
        for (int mi = 0; mi < 4; ++mi)
            ah0[mi] = *(const f16x8*)&bufc[arow + mi * 1024 + g0];

        GLOAD_LDS16(gAh + kn,       &bufn[loff]);
        GLOAD_LDS16(gAh + r64 + kn, &bufn[4096 + loff]);
        GLOAD_LDS16(gAl + kn,       &bufn[ 8192 + loff]);
        GLOAD_LDS16(gAl + r64 + kn, &bufn[12288 + loff]);

        #pragma unroll
        for (int mi = 0; mi < 4; ++mi)
            ah1[mi] = *(const f16x8*)&bufc[arow + mi * 1024 + g1];
        #pragma unroll
        for (int mi = 0; mi < 4; ++mi)
            al0[mi] = *(const f16x8*)&bufc[8192 + arow + mi * 1024 + g0];
        #pragma unroll
        for (int mi = 0; mi < 4; ++mi)
            al1[mi] = *(const f16x8*)&bufc[8192 + arow + mi * 1024 + g1];

        MFMA_TILE(ah0, bv0);
        MFMA_TILE(ah1, bv1);
        MFMA_TILE(al0, bv0);
        MFMA_TILE(al1, bv1);

        SGB(0x20,  8, 0);
        SGB(0x100, 4, 0);
        SGB(0x20,  4, 0);
        SGB(0x100, 12, 0);
        SGB(0x8,  64, 0);

        asm volatile("s_waitcnt vmcnt(0)");
        __builtin_amdgcn_s_barrier();
    }

    #pragma unroll
    for (int mi = 0; mi < 4; ++mi) {
        #pragma unroll
        for (int ni = 0; ni < 4; ++ni) {
            #pragma unroll
            for (int rr = 0; rr < 4; ++rr) {
                const int row = row0 + wm * 64 + mi * 16 + lquad * 4 + rr;
                const int col = col0 + wn * 64 + ni * 16 + lrow;
                Cf[(size_t)row * N + col] = acc[mi][ni][rr];
            }
        }
    }
}

// ===========================================================================
// Split-K pass for the 16 half-dead diagonal jobs (by=2h, bx=h): live region
// is the 128x128 square at (row0=256h, col0=256h). grid = (8 kchunks, 16 jobs).
__global__ __launch_bounds__(256) void gemm_half_splitk(
    const f16* __restrict__ Ah, const f16* __restrict__ Al,
    const f16* __restrict__ B, float* __restrict__ Spart, int Kg)
{
    const int kc = blockIdx.x;       // 0..7
    const int h  = blockIdx.y;       // 0..15
    const int row0 = h * 256;        // == col0
    const int kbeg = kc * 256;

    const int tid   = threadIdx.x;
    const int lane  = tid & 63;
    const int wave  = tid >> 6;
    const int wm    = wave >> 1;
    const int wn    = wave & 1;
    const int lrow  = lane & 15;
    const int lquad = lane >> 4;

    __shared__ f16 sAh[BM * BK];
    __shared__ f16 sAl[BM * BK];
    __shared__ f16 sB [BM * BK];

    const int srow = tid >> 3;
    const int scol = (((tid & 7) ^ ((tid >> 3) & 7))) * 8;
    const int lbase = wave * 512;

    f32x4 acc[4][4];
    const f32x4 fz = {0.f, 0.f, 0.f, 0.f};
    #pragma unroll
    for (int i = 0; i < 4; ++i)
        #pragma unroll
        for (int jj = 0; jj < 4; ++jj) acc[i][jj] = fz;

    for (int k0 = kbeg; k0 < kbeg + 256; k0 += BK) {
        __syncthreads();
        #pragma unroll
        for (int r = 0; r < 4; ++r) {
            const int trow = srow + 32 * r;
            const size_t ga = (size_t)(row0 + trow) * Kg + k0 + scol;
            const int ldst = lbase + r * 2048;
            GLOAD_LDS16(&Ah[ga], &sAh[ldst]);
            GLOAD_LDS16(&Al[ga], &sAl[ldst]);
            GLOAD_LDS16(&B [ga], &sB [ldst]);   // B rows == A rows (diag)
        }
        __syncthreads();

        #pragma unroll
        for (int kk = 0; kk < 2; ++kk) {
            const int grpA = ((kk * 4 + lquad) ^ (lrow & 7)) * 8;
            f16x8 ah[4], al[4], bv[4];
            #pragma unroll
            for (int mi = 0; mi < 4; ++mi) {
                const int off = (wm * 64 + mi * 16 + lrow) * BK + grpA;
                ah[mi] = *reinterpret_cast<const f16x8*>(&sAh[off]);
                al[mi] = *reinterpret_cast<const f16x8*>(&sAl[off]);
            }
            #pragma unroll
            for (int ni = 0; ni < 4; ++ni)
                bv[ni] = *reinterpret_cast<const f16x8*>(
                    &sB[(wn * 64 + ni * 16 + lrow) * BK + grpA]);

            #pragma unroll
            for (int mi = 0; mi < 4; ++mi)
                #pragma unroll
                for (int ni = 0; ni < 4; ++ni) {
                    acc[mi][ni] = __builtin_amdgcn_mfma_f32_16x16x32_f16(
                        ah[mi], bv[ni], acc[mi][ni], 0, 0, 0);
                    acc[mi][ni] = __builtin_amdgcn_mfma_f32_16x16x32_f16(
                        al[mi], bv[ni], acc[mi][ni], 0, 0, 0);
                }
        }
    }

    float* outp = Spart + ((size_t)(kc * 16 + h)) * (128 * 128);
    #pragma unroll
    for (int mi = 0; mi < 4; ++mi) {
        #pragma unroll
        for (int ni = 0; ni < 4; ++ni) {
            #pragma unroll
            for (int r = 0; r < 4; ++r) {
                const int row = wm * 64 + mi * 16 + lquad * 4 + r;
                const int col = wn * 64 + ni * 16 + lrow;
                outp[row * 128 + col] = acc[mi][ni][r];
            }
        }
    }
}

// sum the 8 K-chunk partials of each half job into S. grid = (16, 16 jobs).
__global__ __launch_bounds__(256) void combine_halves(
    const float* __restrict__ Spart, float* __restrict__ S, int n)
{
    const int h = blockIdx.y;
    const int e = (blockIdx.x * 256 + threadIdx.x) * 4;   // 0..16383
    float4 a = *reinterpret_cast<const float4*>(
        &Spart[(size_t)h * (128 * 128) + e]);
    #pragma unroll
    for (int kc = 1; kc < 8; ++kc) {
        const float4 b = *reinterpret_cast<const float4*>(
            &Spart[(size_t)(kc * 16 + h) * (128 * 128) + e]);
        a.x += b.x; a.y += b.y; a.z += b.z; a.w += b.w;
    }
    const int i = e >> 7, jj = e & 127;
    *reinterpret_cast<float4*>(&S[(size_t)(h * 256 + i) * n + h * 256 + jj]) = a;
}

// ===========================================================================
// Pipelined single-term GEMM: C = A @ B^T, TRIPLE-buffered LDS (144 KiB).
// Single-BB pipelined body: reads c0(8) | 6 DMAs (t+2, clamped) | reads c1(8)
// | 2 MFMA clusters; counted vmcnt(6); SGB pin. KCAUSAL: K limited to
// (by+1)*128. XCD swizzle when !KCAUSAL (o keeps heavy-first order instead).
// EPI: 0 = fp32 store, 2 = f16 store.
template <int EPI, bool KCAUSAL>
__global__ __launch_bounds__(512, 2) void gemm8_1t(
    const f16* __restrict__ A, const f16* __restrict__ B,
    float* __restrict__ Cf, f16* __restrict__ Co,
    int M, int N, int K)
{
    int bx, by;
    if (KCAUSAL) {
        bx = blockIdx.x;
        by = (int)gridDim.y - 1 - (int)blockIdx.y;
    } else {
        const int gx  = gridDim.x;
        const int nwg = gx * gridDim.y;
        const int id  = blockIdx.y * gx + blockIdx.x;
        const int cpx = nwg >> 3;
        const int j   = (id & 7) * cpx + (id >> 3);
        bx = j % gx;
        by = j / gx;
    }

    const int tid   = threadIdx.x;
    const int lane  = tid & 63;
    const int wave  = tid >> 6;
    const int wm    = wave >> 2;
    const int wn    = wave & 3;
    const int lrow  = lane & 15;
    const int lquad = lane >> 4;

    __shared__ f16 lds[3][24576];   // 144 KiB total

    const int row0 = by * 128;
    const int col0 = bx * 256;

    const int srow = tid >> 3;
    const int scol = ((tid & 7) ^ (srow & 7)) * 8;
    const int loff = wave * 512;
    const int g0 = ((lquad)     ^ (lrow & 7)) * 8;
    const int g1 = ((4 + lquad) ^ (lrow & 7)) * 8;
    const int arow = (wm * 64 + lrow) * 64;
    const int brow = (wn * 64 + lrow) * 64 + 8192;

    const f16* gA = A + (size_t)(row0 + srow) * K + scol;
    const f16* gB = B + (size_t)(col0 + srow) * K + scol;
    const size_t r64 = (size_t)64 * K;

    f32x4 acc[4][4];
    const f32x4 fz = {0.f, 0.f, 0.f, 0.f};
    #pragma unroll
    for (int i = 0; i < 4; ++i)
        #pragma unroll
        for (int j2 = 0; j2 < 4; ++j2) acc[i][j2] = fz;

    const int Keff = KCAUSAL ? (by + 1) * 128 : K;
    const int nt = Keff / 64;   // >= 2 always (by=0 -> 2)

    // prologue: stage tiles 0 and 1 (order per tile: B0 B1 B2 B3 A0 A1)
    #pragma unroll
    for (int tt = 0; tt < 2; ++tt) {
        const size_t kk = (size_t)tt * 64;
        #pragma unroll
        for (int u = 0; u < 4; ++u)
            GLOAD_LDS16(gB + u * r64 + kk, &lds[tt][8192 + u * 4096 + loff]);
        #pragma unroll
        for (int u = 0; u < 2; ++u)
            GLOAD_LDS16(gA + u * r64 + kk, &lds[tt][u * 4096 + loff]);
    }
    asm volatile("s_waitcnt vmcnt(6)");   // tile 0 landed; tile 1 may fly
    __builtin_amdgcn_s_barrier();

    int cur = 0;
    for (int t = 0; t < nt; ++t) {
        const int nb = (cur >= 1) ? (cur - 1) : (cur + 2);  // (t+2) % 3
        const size_t kn = (size_t)((t + 2 < nt) ? t + 2 : nt - 1) * 64;
        const f16* bufc = &lds[cur][0];
        f16* bufn = &lds[nb][0];

        f16x8 av0[4], av1[4], bv0[4], bv1[4];

        #pragma unroll
        for (int mi = 0; mi < 4; ++mi)
            av0[mi] = *(const f16x8*)&bufc[arow + mi * 1024 + g0];
        #pragma unroll
        for (int ni = 0; ni < 4; ++ni)
            bv0[ni] = *(const f16x8*)&bufc[brow + ni * 1024 + g0];

        GLOAD_LDS16(gB + kn,           &bufn[8192 + loff]);
        GLOAD_LDS16(gB + r64 + kn,     &bufn[8192 +  4096 + loff]);
        GLOAD_LDS16(gB + 2 * r64 + kn, &bufn[8192 +  8192 + loff]);
        GLOAD_LDS16(gB + 3 * r64 + kn, &bufn[8192 + 12288 + loff]);
        GLOAD_LDS16(gA + kn,           &bufn[loff]);
        GLOAD_LDS16(gA + r64 + kn,     &bufn[4096 + loff]);

        #pragma unroll
        for (int mi = 0; mi < 4; ++mi)
            av1[mi] = *(const f16x8*)&bufc[arow + mi * 1024 + g1];
        #pragma unroll
        for (int ni = 0; ni < 4; ++ni)
            bv1[ni] = *(const f16x8*)&bufc[brow + ni * 1024 + g1];

        MFMA_TILE(av0, bv0);
        MFMA_TILE(av1, bv1);

        SGB(0x100, 8, 0);
        SGB(0x20,  6, 0);
        SGB(0x100, 8, 0);
        SGB(0x8,  32, 0);

        // counted drain: the 6 just-issued stay in flight; batch t+1 landed
        asm volatile("s_waitcnt vmcnt(6)");
        __builtin_amdgcn_s_barrier();

        cur = (cur == 2) ? 0 : cur + 1;
    }

    #pragma unroll
    for (int mi = 0; mi < 4; ++mi) {
        #pragma unroll
        for (int ni = 0; ni < 4; ++ni) {
            #pragma unroll
            for (int r = 0; r < 4; ++r) {
                const int row = row0 + wm * 64 + mi * 16 + lquad * 4 + r;
                const int col = col0 + wn * 64 + ni * 16 + lrow;
                const size_t idx = (size_t)row * N + col;
                const float v = acc[mi][ni][r];
                if (EPI == 0) Cf[idx] = v;
                else          Co[idx] = (f16)v;
            }
        }
    }
}

// fp32 -> f16 hi (+ optional lo residual), 4 elems/thread
__global__ __launch_bounds__(256) void split_f32_f16(
    const float* __restrict__ in, f16* __restrict__ hi, f16* __restrict__ lo,
    size_t nelem)
{
    const size_t i = ((size_t)blockIdx.x * 256 + threadIdx.x) * 4;
    if (i >= nelem) return;
    const float4 v = *reinterpret_cast<const float4*>(in + i);
    union { f16 h[4]; ushort4 u; } H, L;
    H.h[0] = (f16)v.x; H.h[1] = (f16)v.y; H.h[2] = (f16)v.z; H.h[3] = (f16)v.w;
    *reinterpret_cast<ushort4*>(hi + i) = H.u;
    if (lo) {
        L.h[0] = (f16)(v.x - (float)H.h[0]);
        L.h[1] = (f16)(v.y - (float)H.h[1]);
        L.h[2] = (f16)(v.z - (float)H.h[2]);
        L.h[3] = (f16)(v.w - (float)H.h[3]);
        *reinterpret_cast<ushort4*>(lo + i) = L.u;
    }
}

// fused: x -> xh (f16 hi), xl (f16 residual), xTh (f16 transpose).
// Reads x exactly once. 32x32 tiles, 256 thr.
__global__ __launch_bounds__(256) void prep_x(
    const float* __restrict__ in, f16* __restrict__ hi, f16* __restrict__ lo,
    f16* __restrict__ tr, int rows, int cols)
{
    __shared__ float tile[32][33];
    const int bx = blockIdx.x;
    const int by = blockIdx.y;
    const int tx = threadIdx.x & 31;
    const int ty = threadIdx.x >> 5;
    #pragma unroll
    for (int r = 0; r < 4; ++r) {
        const int row = by * 32 + ty + 8 * r;
        const int col = bx * 32 + tx;
        const float v = in[(size_t)row * cols + col];
        tile[ty + 8 * r][tx] = v;
        const f16 h = (f16)v;
        hi[(size_t)row * cols + col] = h;
        lo[(size_t)row * cols + col] = (f16)(v - (float)h);
    }
    __syncthreads();
    #pragma unroll
    for (int r = 0; r < 4; ++r)
        tr[(size_t)(bx * 32 + ty + 8 * r) * rows + by * 32 + tx] =
            (f16)tile[tx][ty + 8 * r];
}

// row-wise causal softmax, single global pass (row cached in LDS),
// online max+sum; zero-pads P to the 128 boundary.
__global__ __launch_bounds__(256) void softmax_rows(
    const float* __restrict__ S, f16* __restrict__ P, int n)
{
    const int row = blockIdx.x;
    const int len = row + 1;
    const int padlen = ((row >> 7) + 1) << 7;
    const float* srow = S + (size_t)row * n;
    f16* prow = P + (size_t)row * n;
    const int tid = threadIdx.x;
    const int lane = tid & 63, wave = tid >> 6;
    __shared__ float rowbuf[4096];   // 16 KB row cache (n <= 4096)
    __shared__ float redm[4], reds[4];

    float m = -3.0e38f, s = 0.f;
    for (int j = tid; j < len; j += 256) {
        const float v = srow[j];
        rowbuf[j] = v;
        const float mn = fmaxf(m, v);
        s = s * __expf(m - mn) + __expf(v - mn);
        m = mn;
    }
    #pragma unroll
    for (int off = 32; off; off >>= 1) {
        const float mo = __shfl_xor(m, off, 64);
        const float so = __shfl_xor(s, off, 64);
        const float mn = fmaxf(m, mo);
        s = s * __expf(m - mn) + so * __expf(mo - mn);
        m = mn;
    }
    if (lane == 0) { redm[wave] = m; reds[wave] = s; }
    __syncthreads();
    float M = redm[0], Sm = reds[0];
    #pragma unroll
    for (int w = 1; w < 4; ++w) {
        const float mn = fmaxf(M, redm[w]);
        Sm = Sm * __expf(M - mn) + reds[w] * __expf(redm[w] - mn);
        M = mn;
    }
    const float inv = 1.0f / Sm;

    const f16 z = (f16)0.0f;
    for (int j = tid; j < padlen; j += 256)
        prow[j] = (j < len) ? (f16)(__expf(rowbuf[j] - M) * inv) : z;
}

extern "C" void kernel_launch(void* const* d_in, const int* in_sizes, int n_in,
                              void* d_out, int out_size, void* d_ws, size_t ws_size,
                              hipStream_t stream)
{
    const int n = 4096, d = 2048;
    const float* x   = (const float*)d_in[0];
    const float* Wqk = (const float*)d_in[1];
    const float* Wov = (const float*)d_in[2];
    float* out = (float*)d_out;

    char* ws = (char*)d_ws;
    const size_t MB = 1 << 20;
    f16*   xh   = (f16*)  (ws);             // 16 MB  (n x d)
    f16*   xl   = (f16*)  (ws + 16 * MB);   // 16 MB  (dead after q GEMM)
    f16*   Wh   = (f16*)  (ws + 32 * MB);   //  8 MB  (d x d, dead after q GEMM)
    f16*   Wovh = (f16*)  (ws + 40 * MB);   //  8 MB  (live to end)
    f16*   xTh  = (f16*)  (ws + 48 * MB);   // 16 MB  (d x n, live to o GEMM)
    f16*   qh   = (f16*)  (ws + 64 * MB);   // 16 MB  (dead after S GEMM)
    f16*   ql   = (f16*)  (ws + 80 * MB);   // 16 MB  (dead after S GEMM)
    float* S    = (float*)(ws + 96 * MB);   // 64 MB  (n x n)  -> peak 160 MB
    float* Sp   = (float*)(ws + 16 * MB);   //  8 MB  split-K partials (over xl,
                                            //        dead; freed before P)
    f16*   P    = (f16*)  (ws);             // 32 MB  (n x n), over xh+xl (dead)
    f16*   o    = (f16*)  (ws + 64 * MB);   // 16 MB  (n x d), over qh (dead)

    const dim3 blk(256);
    const dim3 blk8(512);

    // fp32 -> f16 conversions (x split+transpose fused, reads x once)
    split_f32_f16<<<dim3((d * d) / (256 * 4)), blk, 0, stream>>>(Wqk, Wh, nullptr, (size_t)d * d);
    split_f32_f16<<<dim3((d * d) / (256 * 4)), blk, 0, stream>>>(Wov, Wovh, nullptr, (size_t)d * d);
    prep_x<<<dim3(d / 32, n / 32), blk, 0, stream>>>(x, xh, xl, xTh, n, d);

    // q = (xh+xl) @ Wh^T, pipelined 2-term, B-direct-to-reg, f16 hi/lo out
    gemm8_a2<1><<<dim3(d / 256, n / 128), blk8, 0, stream>>>(
        xh, xl, Wh, nullptr, qh, ql, n, d, d);

    // S: 256 fully-live causal jobs, 1 block/CU, perfectly balanced
    gemm8_s_jobs<<<dim3(256), blk8, 0, stream>>>(qh, ql, xh, S, n, d);
    // 16 half-dead diagonal jobs, split-K 8-way, then combine into S
    gemm_half_splitk<<<dim3(8, 16), blk, 0, stream>>>(qh, ql, xh, Sp, d);
    combine_halves<<<dim3(16, 16), blk, 0, stream>>>(Sp, S, n);

    // P = causal row softmax(S), f16, zero-padded to 128 boundary
    softmax_rows<<<dim3(n), blk, 0, stream>>>(S, P, n);

    // o = P @ xTh^T, K causally limited per row-block; 256 blocks = 1/CU,
    // heavy rows dispatched first. K param = stride (n).
    gemm8_1t<2, true><<<dim3(d / 256, n / 128), blk8, 0, stream>>>(
        P, xTh, nullptr, o, n, d, n);

    // out = o @ Wovh^T, pipelined single-term, fp32 store to d_out
    gemm8_1t<0, false><<<dim3(d / 256, n / 128), blk8, 0, stream>>>(
        o, Wovh, out, nullptr, n, d, d);
}

// Round 9
// 362.233 us; speedup vs baseline: 1.2019x; 1.2019x over previous
//
#include <hip/hip_runtime.h>
#include <hip/hip_bf16.h>
#include <stdint.h>
#include <stddef.h>
#include <math.h>

typedef _Float16 f16;
typedef __attribute__((ext_vector_type(8))) _Float16 f16x8;  // 4 VGPRs (MFMA A/B)
typedef __attribute__((ext_vector_type(4))) float    f32x4;  // MFMA C/D

constexpr int BM = 128, BN = 128, BK = 64;   // half-splitk tiles

// async global->LDS DMA, 16 B/lane; LDS dest = wave-uniform base + lane*16
#define GLOAD_LDS16(gp, lp)                                        \
    __builtin_amdgcn_global_load_lds(                              \
        (const __attribute__((address_space(1))) unsigned int*)(gp),\
        (__attribute__((address_space(3))) unsigned int*)(lp), 16, 0, 0)

// one MFMA cluster: 16 x mfma_f32_16x16x32_f16 wrapped in setprio (T5)
#define MFMA_TILE(AV, BV)                                                     \
    do {                                                                      \
        __builtin_amdgcn_s_setprio(1);                                        \
        _Pragma("unroll")                                                     \
        for (int mi_ = 0; mi_ < 4; ++mi_)                                     \
            _Pragma("unroll")                                                 \
            for (int ni_ = 0; ni_ < 4; ++ni_)                                 \
                acc[mi_][ni_] = __builtin_amdgcn_mfma_f32_16x16x32_f16(       \
                    (AV)[mi_], (BV)[ni_], acc[mi_][ni_], 0, 0, 0);            \
        __builtin_amdgcn_s_setprio(0);                                        \
    } while (0)

// ===========================================================================
// Pipelined 2-term GEMM: C = (Ah+Al) @ B^T, f16 in / fp32 accum.
// BM=128, BN=256, BK=64, 512 threads = 8 waves (2M x 4N), 64x64 out/wave.
//
// Round-9 schedule (T4: COUNTED VMCNT, NEVER 0): round 8's B-direct exposed
// per-tile L2 latency (110us, MfmaUtil 25) -> reverted to LDS-staged B.
// Rounds 6/7 measured the vmcnt(0)-per-tile drain structure at 4990 cyc/tile
// = LDS(2816)+MFMA(2483) serial. This version removes the full drain:
//   LDS 160 KiB = A triple-buffer (3 x [Ah 16K|Al 16K]) + B double (2 x 32K).
//   Per tile, 2 phases:
//     ph0: 12 ds_read(g0) | stage B(t+1)x4 | bar | 32 MFMA | bar
//     ph1: 12 ds_read(g1) | stage A(t+2)x4 | vmcnt(4) | bar | 32 MFMA | bar
//   Ledger at vmcnt(4): [A(t+1)4, B(t+1)4, A(t+2)4] outstanding -> leaves
//   A(t+2) flying, confirms A(t+1)+B(t+1) landed for next tile's reads.
//   Prologue: A(0),B(0),A(1) issued; vmcnt(4) leaves A(1) flying = steady.
// Hazards: every buffer overwrite is separated from its last reader by a
// barrier that follows the corresponding vmcnt/lgkm completion.
template <int EPI>
__global__ __launch_bounds__(512, 2) void gemm8_a2(
    const f16* __restrict__ Ah, const f16* __restrict__ Al,
    const f16* __restrict__ B,
    float* __restrict__ Cf, f16* __restrict__ Co, f16* __restrict__ Clo,
    int M, int N, int K)
{
    // bijective XCD remap: id%8 = XCD; XCD k -> contiguous j-range (L2 reuse)
    const int gx  = gridDim.x;
    const int nwg = gx * gridDim.y;
    const int id  = blockIdx.y * gx + blockIdx.x;
    const int cpx = nwg >> 3;
    const int j   = (id & 7) * cpx + (id >> 3);
    const int bx  = j % gx;
    const int by  = j / gx;

    const int tid   = threadIdx.x;
    const int lane  = tid & 63;
    const int wave  = tid >> 6;   // 0..7
    const int wm    = wave >> 2;  // 0..1  (M)
    const int wn    = wave & 3;   // 0..3  (N)
    const int lrow  = lane & 15;
    const int lquad = lane >> 4;

    __shared__ f16 ldsA[3][16384];  // 96 KiB: per buf [Ah 16K | Al 16K]
    __shared__ f16 ldsB[2][16384];  // 64 KiB: per buf 256 rows x 64

    const int row0 = by * 128;
    const int col0 = bx * 256;

    const int srow = tid >> 3;                       // 0..63 (row within unit)
    const int scol = ((tid & 7) ^ (srow & 7)) * 8;   // pre-swizzled source col
    const int loff = wave * 512;                     // wave slice inside a unit

    const int g0 = ((lquad)     ^ (lrow & 7)) * 8;   // swizzled group, kk=0
    const int g1 = ((4 + lquad) ^ (lrow & 7)) * 8;   // swizzled group, kk=1

    const int arow = (wm * 64 + lrow) * 64;           // A frag base (elems)
    const int brow = (wn * 64 + lrow) * 64;           // B frag base (elems)

    const f16* gAh = Ah + (size_t)(row0 + srow) * K + scol;
    const f16* gAl = Al + (size_t)(row0 + srow) * K + scol;
    const f16* gB  = B  + (size_t)(col0 + srow) * K + scol;
    const size_t r64 = (size_t)64 * K;

    f32x4 acc[4][4];
    const f32x4 fz = {0.f, 0.f, 0.f, 0.f};
    #pragma unroll
    for (int i = 0; i < 4; ++i)
        #pragma unroll
        for (int jj = 0; jj < 4; ++jj) acc[i][jj] = fz;

    const int nt = K / 64;

    // prologue: A(0), B(0), A(1); counted wait leaves A(1) in flight
    GLOAD_LDS16(gAh,       &ldsA[0][loff]);
    GLOAD_LDS16(gAh + r64, &ldsA[0][4096 + loff]);
    GLOAD_LDS16(gAl,       &ldsA[0][8192 + loff]);
    GLOAD_LDS16(gAl + r64, &ldsA[0][12288 + loff]);
    #pragma unroll
    for (int u = 0; u < 4; ++u)
        GLOAD_LDS16(gB + u * r64, &ldsB[0][u * 4096 + loff]);
    GLOAD_LDS16(gAh + 64,       &ldsA[1][loff]);
    GLOAD_LDS16(gAh + r64 + 64, &ldsA[1][4096 + loff]);
    GLOAD_LDS16(gAl + 64,       &ldsA[1][8192 + loff]);
    GLOAD_LDS16(gAl + r64 + 64, &ldsA[1][12288 + loff]);
    asm volatile("s_waitcnt vmcnt(4)");   // A(0)+B(0) landed; A(1) flying
    __builtin_amdgcn_s_barrier();

    int aidx = 0;                          // t % 3
    for (int t = 0; t < nt; ++t) {
        const f16* bA = &ldsA[aidx][0];
        const f16* bB = &ldsB[t & 1][0];
        f16* nA = &ldsA[(aidx + 2 >= 3) ? aidx - 1 : aidx + 2][0];  // (t+2)%3
        f16* nB = &ldsB[(t + 1) & 1][0];
        // branchless clamped prefetch targets (refetch is harmless)
        const size_t kB1 = (size_t)((t + 1 < nt) ? t + 1 : nt - 1) * 64;
        const size_t kA2 = (size_t)((t + 2 < nt) ? t + 2 : nt - 1) * 64;

        f16x8 ah0[4], al0[4], bv0[4], ah1[4], al1[4], bv1[4];

        // ---------- phase 0: g0 fragments, stage B(t+1) ----------
        #pragma unroll
        for (int mi = 0; mi < 4; ++mi)
            ah0[mi] = *(const f16x8*)&bA[arow + mi * 1024 + g0];
        #pragma unroll
        for (int ni = 0; ni < 4; ++ni)
            bv0[ni] = *(const f16x8*)&bB[brow + ni * 1024 + g0];
        #pragma unroll
        for (int mi = 0; mi < 4; ++mi)
            al0[mi] = *(const f16x8*)&bA[8192 + arow + mi * 1024 + g0];

        #pragma unroll
        for (int u = 0; u < 4; ++u)
            GLOAD_LDS16(gB + u * r64 + kB1, &nB[u * 4096 + loff]);

        __builtin_amdgcn_s_barrier();
        MFMA_TILE(ah0, bv0);
        MFMA_TILE(al0, bv0);
        __builtin_amdgcn_s_barrier();

        // ---------- phase 1: g1 fragments, stage A(t+2), counted wait ------
        #pragma unroll
        for (int mi = 0; mi < 4; ++mi)
            ah1[mi] = *(const f16x8*)&bA[arow + mi * 1024 + g1];
        #pragma unroll
        for (int ni = 0; ni < 4; ++ni)
            bv1[ni] = *(const f16x8*)&bB[brow + ni * 1024 + g1];
        #pragma unroll
        for (int mi = 0; mi < 4; ++mi)
            al1[mi] = *(const f16x8*)&bA[8192 + arow + mi * 1024 + g1];

        GLOAD_LDS16(gAh + kA2,       &nA[loff]);
        GLOAD_LDS16(gAh + r64 + kA2, &nA[4096 + loff]);
        GLOAD_LDS16(gAl + kA2,       &nA[8192 + loff]);
        GLOAD_LDS16(gAl + r64 + kA2, &nA[12288 + loff]);

        asm volatile("s_waitcnt vmcnt(4)");   // A(t+1)+B(t+1) landed
        __builtin_amdgcn_s_barrier();
        MFMA_TILE(ah1, bv1);
        MFMA_TILE(al1, bv1);
        __builtin_amdgcn_s_barrier();

        aidx = (aidx == 2) ? 0 : aidx + 1;
    }

    // epilogue: D element (row = lquad*4 + r, col = lrow) within 16x16 tiles
    #pragma unroll
    for (int mi = 0; mi < 4; ++mi) {
        #pragma unroll
        for (int ni = 0; ni < 4; ++ni) {
            #pragma unroll
            for (int r = 0; r < 4; ++r) {
                const int row = row0 + wm * 64 + mi * 16 + lquad * 4 + r;
                const int col = col0 + wn * 64 + ni * 16 + lrow;
                const size_t idx = (size_t)row * N + col;
                const float v = acc[mi][ni][r];
                if (EPI == 0) {
                    Cf[idx] = v;
                } else {
                    const f16 h = (f16)v;
                    Co[idx]  = h;
                    Clo[idx] = (f16)(v - (float)h);
                }
            }
        }
    }
}

// ===========================================================================
// S-GEMM main dispatch: the 256 FULLY-LIVE causal jobs, one block each,
// perfectly balanced 1 block/CU. Job map: r = floor(sqrt(j)); u = j - r^2;
// (by,bx) = u<r ? (2r, u) : (2r+1, u-r). XCD remap b -> j = (b&7)*32 + (b>>3).
// Same counted-vmcnt 2-phase body as gemm8_a2.
__global__ __launch_bounds__(512, 2) void gemm8_s_jobs(
    const f16* __restrict__ Ah, const f16* __restrict__ Al,
    const f16* __restrict__ B,
    float* __restrict__ Cf, int N, int K)
{
    const int b = blockIdx.x;
    const int j = (b & 7) * 32 + (b >> 3);
    int r = (int)sqrtf((float)j);
    while (r * r > j) --r;
    while ((r + 1) * (r + 1) <= j) ++r;
    const int u = j - r * r;
    const int by = (u < r) ? 2 * r : 2 * r + 1;
    const int bx = (u < r) ? u : u - r;

    const int tid   = threadIdx.x;
    const int lane  = tid & 63;
    const int wave  = tid >> 6;
    const int wm    = wave >> 2;
    const int wn    = wave & 3;
    const int lrow  = lane & 15;
    const int lquad = lane >> 4;

    __shared__ f16 ldsA[3][16384];  // 96 KiB
    __shared__ f16 ldsB[2][16384];  // 64 KiB

    const int row0 = by * 128;
    const int col0 = bx * 256;

    const int srow = tid >> 3;
    const int scol = ((tid & 7) ^ (srow & 7)) * 8;
    const int loff = wave * 512;

    const int g0 = ((lquad)     ^ (lrow & 7)) * 8;
    const int g1 = ((4 + lquad) ^ (lrow & 7)) * 8;

    const int arow = (wm * 64 + lrow) * 64;
    const int brow = (wn * 64 + lrow) * 64;

    const f16* gAh = Ah + (size_t)(row0 + srow) * K + scol;
    const f16* gAl = Al + (size_t)(row0 + srow) * K + scol;
    const f16* gB  = B  + (size_t)(col0 + srow) * K + scol;
    const size_t r64 = (size_t)64 * K;

    f32x4 acc[4][4];
    const f32x4 fz = {0.f, 0.f, 0.f, 0.f};
    #pragma unroll
    for (int i = 0; i < 4; ++i)
        #pragma unroll
        for (int jj = 0; jj < 4; ++jj) acc[i][jj] = fz;

    const int nt = K / 64;

    GLOAD_LDS16(gAh,       &ldsA[0][loff]);
    GLOAD_LDS16(gAh + r64, &ldsA[0][4096 + loff]);
    GLOAD_LDS16(gAl,       &ldsA[0][8192 + loff]);
    GLOAD_LDS16(gAl + r64, &ldsA[0][12288 + loff]);
    #pragma unroll
    for (int u2 = 0; u2 < 4; ++u2)
        GLOAD_LDS16(gB + u2 * r64, &ldsB[0][u2 * 4096 + loff]);
    GLOAD_LDS16(gAh + 64,       &ldsA[1][loff]);
    GLOAD_LDS16(gAh + r64 + 64, &ldsA[1][4096 + loff]);
    GLOAD_LDS16(gAl + 64,       &ldsA[1][8192 + loff]);
    GLOAD_LDS16(gAl + r64 + 64, &ldsA[1][12288 + loff]);
    asm volatile("s_waitcnt vmcnt(4)");
    __builtin_amdgcn_s_barrier();

    int aidx = 0;
    for (int t = 0; t < nt; ++t) {
        const f16* bA = &ldsA[aidx][0];
        const f16* bB = &ldsB[t & 1][0];
        f16* nA = &ldsA[(aidx + 2 >= 3) ? aidx - 1 : aidx + 2][0];
        f16* nB = &ldsB[(t + 1) & 1][0];
        const size_t kB1 = (size_t)((t + 1 < nt) ? t + 1 : nt - 1) * 64;
        const size_t kA2 = (size_t)((t + 2 < nt) ? t + 2 : nt - 1) * 64;

        f16x8 ah0[4], al0[4], bv0[4], ah1[4], al1[4], bv1[4];

        // phase 0
        #pragma unroll
        for (int mi = 0; mi < 4; ++mi)
            ah0[mi] = *(const f16x8*)&bA[arow + mi * 1024 + g0];
        #pragma unroll
        for (int ni = 0; ni < 4; ++ni)
            bv0[ni] = *(const f16x8*)&bB[brow + ni * 1024 + g0];
        #pragma unroll
        for (int mi = 0; mi < 4; ++mi)
            al0[mi] = *(const f16x8*)&bA[8192 + arow + mi * 1024 + g0];

        #pragma unroll
        for (int u2 = 0; u2 < 4; ++u2)
            GLOAD_LDS16(gB + u2 * r64 + kB1, &nB[u2 * 4096 + loff]);

        __builtin_amdgcn_s_barrier();
        MFMA_TILE(ah0, bv0);
        MFMA_TILE(al0, bv0);
        __builtin_amdgcn_s_barrier();

        // phase 1
        #pragma unroll
        for (int mi = 0; mi < 4; ++mi)
            ah1[mi] = *(const f16x8*)&bA[arow + mi * 1024 + g1];
        #pragma unroll
        for (int ni = 0; ni < 4; ++ni)
            bv1[ni] = *(const f16x8*)&bB[brow + ni * 1024 + g1];
        #pragma unroll
        for (int mi = 0; mi < 4; ++mi)
            al1[mi] = *(const f16x8*)&bA[8192 + arow + mi * 1024 + g1];

        GLOAD_LDS16(gAh + kA2,       &nA[loff]);
        GLOAD_LDS16(gAh + r64 + kA2, &nA[4096 + loff]);
        GLOAD_LDS16(gAl + kA2,       &nA[8192 + loff]);
        GLOAD_LDS16(gAl + r64 + kA2, &nA[12288 + loff]);

        asm volatile("s_waitcnt vmcnt(4)");
        __builtin_amdgcn_s_barrier();
        MFMA_TILE(ah1, bv1);
        MFMA_TILE(al1, bv1);
        __builtin_amdgcn_s_barrier();

        aidx = (aidx == 2) ? 0 : aidx + 1;
    }

    #pragma unroll
    for (int mi = 0; mi < 4; ++mi) {
        #pragma unroll
        for (int ni = 0; ni < 4; ++ni) {
            #pragma unroll
            for (int rr = 0; rr < 4; ++rr) {
                const int row = row0 + wm * 64 + mi * 16 + lquad * 4 + rr;
                const int col = col0 + wn * 64 + ni * 16 + lrow;
                Cf[(size_t)row * N + col] = acc[mi][ni][rr];
            }
        }
    }
}

// ===========================================================================
// Split-K pass for the 16 half-dead diagonal jobs (by=2h, bx=h): live region
// is the 128x128 square at (row0=256h, col0=256h). grid = (8 kchunks, 16 jobs).
__global__ __launch_bounds__(256) void gemm_half_splitk(
    const f16* __restrict__ Ah, const f16* __restrict__ Al,
    const f16* __restrict__ B, float* __restrict__ Spart, int Kg)
{
    const int kc = blockIdx.x;       // 0..7
    const int h  = blockIdx.y;       // 0..15
    const int row0 = h * 256;        // == col0
    const int kbeg = kc * 256;

    const int tid   = threadIdx.x;
    const int lane  = tid & 63;
    const int wave  = tid >> 6;
    const int wm    = wave >> 1;
    const int wn    = wave & 1;
    const int lrow  = lane & 15;
    const int lquad = lane >> 4;

    __shared__ f16 sAh[BM * BK];
    __shared__ f16 sAl[BM * BK];
    __shared__ f16 sB [BM * BK];

    const int srow = tid >> 3;
    const int scol = (((tid & 7) ^ ((tid >> 3) & 7))) * 8;
    const int lbase = wave * 512;

    f32x4 acc[4][4];
    const f32x4 fz = {0.f, 0.f, 0.f, 0.f};
    #pragma unroll
    for (int i = 0; i < 4; ++i)
        #pragma unroll
        for (int jj = 0; jj < 4; ++jj) acc[i][jj] = fz;

    for (int k0 = kbeg; k0 < kbeg + 256; k0 += BK) {
        __syncthreads();
        #pragma unroll
        for (int r = 0; r < 4; ++r) {
            const int trow = srow + 32 * r;
            const size_t ga = (size_t)(row0 + trow) * Kg + k0 + scol;
            const int ldst = lbase + r * 2048;
            GLOAD_LDS16(&Ah[ga], &sAh[ldst]);
            GLOAD_LDS16(&Al[ga], &sAl[ldst]);
            GLOAD_LDS16(&B [ga], &sB [ldst]);   // B rows == A rows (diag)
        }
        __syncthreads();

        #pragma unroll
        for (int kk = 0; kk < 2; ++kk) {
            const int grpA = ((kk * 4 + lquad) ^ (lrow & 7)) * 8;
            f16x8 ah[4], al[4], bv[4];
            #pragma unroll
            for (int mi = 0; mi < 4; ++mi) {
                const int off = (wm * 64 + mi * 16 + lrow) * BK + grpA;
                ah[mi] = *reinterpret_cast<const f16x8*>(&sAh[off]);
                al[mi] = *reinterpret_cast<const f16x8*>(&sAl[off]);
            }
            #pragma unroll
            for (int ni = 0; ni < 4; ++ni)
                bv[ni] = *reinterpret_cast<const f16x8*>(
                    &sB[(wn * 64 + ni * 16 + lrow) * BK + grpA]);

            #pragma unroll
            for (int mi = 0; mi < 4; ++mi)
                #pragma unroll
                for (int ni = 0; ni < 4; ++ni) {
                    acc[mi][ni] = __builtin_amdgcn_mfma_f32_16x16x32_f16(
                        ah[mi], bv[ni], acc[mi][ni], 0, 0, 0);
                    acc[mi][ni] = __builtin_amdgcn_mfma_f32_16x16x32_f16(
                        al[mi], bv[ni], acc[mi][ni], 0, 0, 0);
                }
        }
    }

    float* outp = Spart + ((size_t)(kc * 16 + h)) * (128 * 128);
    #pragma unroll
    for (int mi = 0; mi < 4; ++mi) {
        #pragma unroll
        for (int ni = 0; ni < 4; ++ni) {
            #pragma unroll
            for (int r = 0; r < 4; ++r) {
                const int row = wm * 64 + mi * 16 + lquad * 4 + r;
                const int col = wn * 64 + ni * 16 + lrow;
                outp[row * 128 + col] = acc[mi][ni][r];
            }
        }
    }
}

// sum the 8 K-chunk partials of each half job into S. grid = (16, 16 jobs).
__global__ __launch_bounds__(256) void combine_halves(
    const float* __restrict__ Spart, float* __restrict__ S, int n)
{
    const int h = blockIdx.y;
    const int e = (blockIdx.x * 256 + threadIdx.x) * 4;   // 0..16383
    float4 a = *reinterpret_cast<const float4*>(
        &Spart[(size_t)h * (128 * 128) + e]);
    #pragma unroll
    for (int kc = 1; kc < 8; ++kc) {
        const float4 b = *reinterpret_cast<const float4*>(
            &Spart[(size_t)(kc * 16 + h) * (128 * 128) + e]);
        a.x += b.x; a.y += b.y; a.z += b.z; a.w += b.w;
    }
    const int i = e >> 7, jj = e & 127;
    *reinterpret_cast<float4*>(&S[(size_t)(h * 256 + i) * n + h * 256 + jj]) = a;
}

// ===========================================================================
// Pipelined single-term GEMM: C = A @ B^T, TRIPLE-buffered LDS (144 KiB).
// Single-barrier K-tile body (round-6 verified): 16 fragment reads up front,
// 6 DMAs (tile t+2) follow, 2 MFMA clusters, counted vmcnt(6), one barrier.
// KCAUSAL: K limited to (by+1)*128 (P rows zero-padded to that boundary).
// EPI: 0 = fp32 store, 2 = f16 store.
template <int EPI, bool KCAUSAL>
__global__ __launch_bounds__(512, 2) void gemm8_1t(
    const f16* __restrict__ A, const f16* __restrict__ B,
    float* __restrict__ Cf, f16* __restrict__ Co,
    int M, int N, int K)
{
    const int bx = blockIdx.x;
    const int by = KCAUSAL ? ((int)gridDim.y - 1 - (int)blockIdx.y) : blockIdx.y;

    const int tid   = threadIdx.x;
    const int lane  = tid & 63;
    const int wave  = tid >> 6;
    const int wm    = wave >> 2;
    const int wn    = wave & 3;
    const int lrow  = lane & 15;
    const int lquad = lane >> 4;

    __shared__ f16 lds[3][24576];   // 144 KiB total

    const int row0 = by * 128;
    const int col0 = bx * 256;

    const int srow = tid >> 3;
    const int scol = ((tid & 7) ^ (srow & 7)) * 8;
    const int loff = wave * 512;
    const int g0 = ((lquad)     ^ (lrow & 7)) * 8;
    const int g1 = ((4 + lquad) ^ (lrow & 7)) * 8;
    const int arow = (wm * 64 + lrow) * 64;
    const int brow = (wn * 64 + lrow) * 64 + 8192;

    const f16* gA = A + (size_t)(row0 + srow) * K + scol;
    const f16* gB = B + (size_t)(col0 + srow) * K + scol;
    const size_t r64 = (size_t)64 * K;

    f32x4 acc[4][4];
    const f32x4 fz = {0.f, 0.f, 0.f, 0.f};
    #pragma unroll
    for (int i = 0; i < 4; ++i)
        #pragma unroll
        for (int j = 0; j < 4; ++j) acc[i][j] = fz;

    const int Keff = KCAUSAL ? (by + 1) * 128 : K;
    const int nt = Keff / 64;   // >= 2 always (by=0 -> 2)

    // prologue: stage tiles 0 and 1 (order per tile: B0 B1 B2 B3 A0 A1)
    #pragma unroll
    for (int tt = 0; tt < 2; ++tt) {
        const size_t kk = (size_t)tt * 64;
        #pragma unroll
        for (int u = 0; u < 4; ++u)
            GLOAD_LDS16(gB + u * r64 + kk, &lds[tt][8192 + u * 4096 + loff]);
        #pragma unroll
        for (int u = 0; u < 2; ++u)
            GLOAD_LDS16(gA + u * r64 + kk, &lds[tt][u * 4096 + loff]);
    }
    asm volatile("s_waitcnt vmcnt(6)");   // tile 0 landed; tile 1 may fly
    __builtin_amdgcn_s_barrier();

    int cur = 0;
    for (int t = 0; t < nt; ++t) {
        const int nb = (cur >= 1) ? (cur - 1) : (cur + 2);  // (t+2) % 3
        const bool stage2 = (t + 2 < nt);
        const size_t kn = (size_t)(t + 2) * 64;
        const f16* bufc = &lds[cur][0];
        f16* bufn = &lds[nb][0];

        f16x8 av0[4], av1[4], bv0[4], bv1[4];

        #pragma unroll
        for (int mi = 0; mi < 4; ++mi)
            av0[mi] = *(const f16x8*)&bufc[arow + mi * 1024 + g0];
        #pragma unroll
        for (int ni = 0; ni < 4; ++ni)
            bv0[ni] = *(const f16x8*)&bufc[brow + ni * 1024 + g0];
        #pragma unroll
        for (int mi = 0; mi < 4; ++mi)
            av1[mi] = *(const f16x8*)&bufc[arow + mi * 1024 + g1];
        #pragma unroll
        for (int ni = 0; ni < 4; ++ni)
            bv1[ni] = *(const f16x8*)&bufc[brow + ni * 1024 + g1];

        if (stage2) {
            GLOAD_LDS16(gB + kn,           &bufn[8192 + loff]);
            GLOAD_LDS16(gB + r64 + kn,     &bufn[8192 +  4096 + loff]);
            GLOAD_LDS16(gB + 2 * r64 + kn, &bufn[8192 +  8192 + loff]);
            GLOAD_LDS16(gB + 3 * r64 + kn, &bufn[8192 + 12288 + loff]);
            GLOAD_LDS16(gA + kn,           &bufn[loff]);
            GLOAD_LDS16(gA + r64 + kn,     &bufn[4096 + loff]);
        }

        MFMA_TILE(av0, bv0);
        MFMA_TILE(av1, bv1);

        if (stage2) asm volatile("s_waitcnt vmcnt(6)");  // drain t+1 batch
        else        asm volatile("s_waitcnt vmcnt(0)");  // pipeline tail
        __builtin_amdgcn_s_barrier();

        cur = (cur == 2) ? 0 : cur + 1;
    }

    #pragma unroll
    for (int mi = 0; mi < 4; ++mi) {
        #pragma unroll
        for (int ni = 0; ni < 4; ++ni) {
            #pragma unroll
            for (int r = 0; r < 4; ++r) {
                const int row = row0 + wm * 64 + mi * 16 + lquad * 4 + r;
                const int col = col0 + wn * 64 + ni * 16 + lrow;
                const size_t idx = (size_t)row * N + col;
                const float v = acc[mi][ni][r];
                if (EPI == 0) Cf[idx] = v;
                else          Co[idx] = (f16)v;
            }
        }
    }
}

// fp32 -> f16 hi (+ optional lo residual), 4 elems/thread
__global__ __launch_bounds__(256) void split_f32_f16(
    const float* __restrict__ in, f16* __restrict__ hi, f16* __restrict__ lo,
    size_t nelem)
{
    const size_t i = ((size_t)blockIdx.x * 256 + threadIdx.x) * 4;
    if (i >= nelem) return;
    const float4 v = *reinterpret_cast<const float4*>(in + i);
    union { f16 h[4]; ushort4 u; } H, L;
    H.h[0] = (f16)v.x; H.h[1] = (f16)v.y; H.h[2] = (f16)v.z; H.h[3] = (f16)v.w;
    *reinterpret_cast<ushort4*>(hi + i) = H.u;
    if (lo) {
        L.h[0] = (f16)(v.x - (float)H.h[0]);
        L.h[1] = (f16)(v.y - (float)H.h[1]);
        L.h[2] = (f16)(v.z - (float)H.h[2]);
        L.h[3] = (f16)(v.w - (float)H.h[3]);
        *reinterpret_cast<ushort4*>(lo + i) = L.u;
    }
}

// fused: x -> xh (f16 hi), xl (f16 residual), xTh (f16 transpose).
// Reads x exactly once. 32x32 tiles, 256 thr.
__global__ __launch_bounds__(256) void prep_x(
    const float* __restrict__ in, f16* __restrict__ hi, f16* __restrict__ lo,
    f16* __restrict__ tr, int rows, int cols)
{
    __shared__ float tile[32][33];
    const int bx = blockIdx.x;
    const int by = blockIdx.y;
    const int tx = threadIdx.x & 31;
    const int ty = threadIdx.x >> 5;
    #pragma unroll
    for (int r = 0; r < 4; ++r) {
        const int row = by * 32 + ty + 8 * r;
        const int col = bx * 32 + tx;
        const float v = in[(size_t)row * cols + col];
        tile[ty + 8 * r][tx] = v;
        const f16 h = (f16)v;
        hi[(size_t)row * cols + col] = h;
        lo[(size_t)row * cols + col] = (f16)(v - (float)h);
    }
    __syncthreads();
    #pragma unroll
    for (int r = 0; r < 4; ++r)
        tr[(size_t)(bx * 32 + ty + 8 * r) * rows + by * 32 + tx] =
            (f16)tile[tx][ty + 8 * r];
}

// row-wise causal softmax, single global pass (row cached in LDS),
// online max+sum; zero-pads P to the 128 boundary.
__global__ __launch_bounds__(256) void softmax_rows(
    const float* __restrict__ S, f16* __restrict__ P, int n)
{
    const int row = blockIdx.x;
    const int len = row + 1;
    const int padlen = ((row >> 7) + 1) << 7;
    const float* srow = S + (size_t)row * n;
    f16* prow = P + (size_t)row * n;
    const int tid = threadIdx.x;
    const int lane = tid & 63, wave = tid >> 6;
    __shared__ float rowbuf[4096];   // 16 KB row cache (n <= 4096)
    __shared__ float redm[4], reds[4];

    float m = -3.0e38f, s = 0.f;
    for (int j = tid; j < len; j += 256) {
        const float v = srow[j];
        rowbuf[j] = v;
        const float mn = fmaxf(m, v);
        s = s * __expf(m - mn) + __expf(v - mn);
        m = mn;
    }
    #pragma unroll
    for (int off = 32; off; off >>= 1) {
        const float mo = __shfl_xor(m, off, 64);
        const float so = __shfl_xor(s, off, 64);
        const float mn = fmaxf(m, mo);
        s = s * __expf(m - mn) + so * __expf(mo - mn);
        m = mn;
    }
    if (lane == 0) { redm[wave] = m; reds[wave] = s; }
    __syncthreads();
    float M = redm[0], Sm = reds[0];
    #pragma unroll
    for (int w = 1; w < 4; ++w) {
        const float mn = fmaxf(M, redm[w]);
        Sm = Sm * __expf(M - mn) + reds[w] * __expf(redm[w] - mn);
        M = mn;
    }
    const float inv = 1.0f / Sm;

    const f16 z = (f16)0.0f;
    for (int j = tid; j < padlen; j += 256)
        prow[j] = (j < len) ? (f16)(__expf(rowbuf[j] - M) * inv) : z;
}

extern "C" void kernel_launch(void* const* d_in, const int* in_sizes, int n_in,
                              void* d_out, int out_size, void* d_ws, size_t ws_size,
                              hipStream_t stream)
{
    const int n = 4096, d = 2048;
    const float* x   = (const float*)d_in[0];
    const float* Wqk = (const float*)d_in[1];
    const float* Wov = (const float*)d_in[2];
    float* out = (float*)d_out;

    char* ws = (char*)d_ws;
    const size_t MB = 1 << 20;
    f16*   xh   = (f16*)  (ws);             // 16 MB  (n x d)
    f16*   xl   = (f16*)  (ws + 16 * MB);   // 16 MB  (dead after q GEMM)
    f16*   Wh   = (f16*)  (ws + 32 * MB);   //  8 MB  (d x d, dead after q GEMM)
    f16*   Wovh = (f16*)  (ws + 40 * MB);   //  8 MB  (live to end)
    f16*   xTh  = (f16*)  (ws + 48 * MB);   // 16 MB  (d x n, live to o GEMM)
    f16*   qh   = (f16*)  (ws + 64 * MB);   // 16 MB  (dead after S GEMM)
    f16*   ql   = (f16*)  (ws + 80 * MB);   // 16 MB  (dead after S GEMM)
    float* S    = (float*)(ws + 96 * MB);   // 64 MB  (n x n)  -> peak 160 MB
    float* Sp   = (float*)(ws + 16 * MB);   //  8 MB  split-K partials (over xl,
                                            //        dead; freed before P)
    f16*   P    = (f16*)  (ws);             // 32 MB  (n x n), over xh+xl (dead)
    f16*   o    = (f16*)  (ws + 64 * MB);   // 16 MB  (n x d), over qh (dead)

    const dim3 blk(256);
    const dim3 blk8(512);

    // fp32 -> f16 conversions (x split+transpose fused, reads x once)
    split_f32_f16<<<dim3((d * d) / (256 * 4)), blk, 0, stream>>>(Wqk, Wh, nullptr, (size_t)d * d);
    split_f32_f16<<<dim3((d * d) / (256 * 4)), blk, 0, stream>>>(Wov, Wovh, nullptr, (size_t)d * d);
    prep_x<<<dim3(d / 32, n / 32), blk, 0, stream>>>(x, xh, xl, xTh, n, d);

    // q = (xh+xl) @ Wh^T, 2-phase counted-vmcnt pipeline, f16 hi/lo out
    gemm8_a2<1><<<dim3(d / 256, n / 128), blk8, 0, stream>>>(
        xh, xl, Wh, nullptr, qh, ql, n, d, d);

    // S: 256 fully-live causal jobs, 1 block/CU, perfectly balanced
    gemm8_s_jobs<<<dim3(256), blk8, 0, stream>>>(qh, ql, xh, S, n, d);
    // 16 half-dead diagonal jobs, split-K 8-way, then combine into S
    gemm_half_splitk<<<dim3(8, 16), blk, 0, stream>>>(qh, ql, xh, Sp, d);
    combine_halves<<<dim3(16, 16), blk, 0, stream>>>(Sp, S, n);

    // P = causal row softmax(S), f16, zero-padded to 128 boundary
    softmax_rows<<<dim3(n), blk, 0, stream>>>(S, P, n);

    // o = P @ xTh^T, K causally limited per row-block; 256 blocks = 1/CU,
    // heavy rows dispatched first. K param = stride (n).
    gemm8_1t<2, true><<<dim3(d / 256, n / 128), blk8, 0, stream>>>(
        P, xTh, nullptr, o, n, d, n);

    // out = o @ Wovh^T, pipelined single-term, fp32 store to d_out
    gemm8_1t<0, false><<<dim3(d / 256, n / 128), blk8, 0, stream>>>(
        o, Wovh, out, nullptr, n, d, d);
}